// Round 11
// baseline (172.810 us; speedup 1.0000x reference)
//
#include <hip/hip_runtime.h>
#include <hip/hip_bf16.h>

#define S_  384
#define H_  256
#define NH_ 8
#define DH_ 32
#define B_  4
#define PADK 388

typedef _Float16 f16x8 __attribute__((ext_vector_type(8)));
typedef _Float16 f16x4 __attribute__((ext_vector_type(4)));
typedef _Float16 f16x2 __attribute__((ext_vector_type(2)));
typedef float    f32x4 __attribute__((ext_vector_type(4)));

// ---------------- Kernel P: fused QKV projections ----------------
// z==0 -> Qb (f32), z==1 -> Kf (f16), z==2 -> Vtf (f16, transposed [b][c][s])
__global__ __launch_bounds__(256) void proj_kernel(
    const float* __restrict__ query, const float* __restrict__ key, const float* __restrict__ value,
    const float* __restrict__ Wq, const float* __restrict__ bq,
    const float* __restrict__ Wk, const float* __restrict__ bk,
    const float* __restrict__ Wv, const float* __restrict__ bv,
    float* __restrict__ Qb, _Float16* __restrict__ Kf, _Float16* __restrict__ Vtf)
{
    __shared__ __align__(16) float As[32][36];
    __shared__ __align__(16) float Bs[32][68];
    const int t = threadIdx.x;
    const int m0g = blockIdx.x * 32;
    const int n0g = blockIdx.y * 64;
    const int z = blockIdx.z;
    const float* X    = (z == 0) ? query : (z == 1 ? key : value);
    const float* W    = (z == 0) ? Wq    : (z == 1 ? Wk  : Wv);
    const float* bias = (z == 0) ? bq    : (z == 1 ? bk  : bv);

    const int tn = (t & 15) * 4;
    const int tm = (t >> 4) * 2;
    float acc0[4] = {0.f,0.f,0.f,0.f};
    float acc1[4] = {0.f,0.f,0.f,0.f};

    const int ar = t >> 3, ac4 = (t & 7) * 4;
    const int brr = t >> 4, bc4 = (t & 15) * 4;

    for (int kt = 0; kt < 8; ++kt) {
        const int k0 = kt * 32;
        float4 av  = *(const float4*)&X[(size_t)(m0g + ar) * H_ + k0 + ac4];
        float4 bv0 = *(const float4*)&W[(size_t)(k0 + brr)      * H_ + n0g + bc4];
        float4 bv1 = *(const float4*)&W[(size_t)(k0 + brr + 16) * H_ + n0g + bc4];
        *(float4*)&As[ar][ac4] = av;
        *(float4*)&Bs[brr][bc4] = bv0;
        *(float4*)&Bs[brr + 16][bc4] = bv1;
        __syncthreads();
        #pragma unroll
        for (int c = 0; c < 32; ++c) {
            const float a0 = As[tm][c], a1 = As[tm + 1][c];
            const float4 b4 = *(const float4*)&Bs[c][tn];
            acc0[0] += a0 * b4.x; acc0[1] += a0 * b4.y; acc0[2] += a0 * b4.z; acc0[3] += a0 * b4.w;
            acc1[0] += a1 * b4.x; acc1[1] += a1 * b4.y; acc1[2] += a1 * b4.z; acc1[3] += a1 * b4.w;
        }
        __syncthreads();
    }
    const float4 bi = *(const float4*)&bias[n0g + tn];
    float4 o0 = make_float4(acc0[0] + bi.x, acc0[1] + bi.y, acc0[2] + bi.z, acc0[3] + bi.w);
    float4 o1 = make_float4(acc1[0] + bi.x, acc1[1] + bi.y, acc1[2] + bi.z, acc1[3] + bi.w);
    if (z == 1) {
        f16x4 h0 = { (_Float16)o0.x, (_Float16)o0.y, (_Float16)o0.z, (_Float16)o0.w };
        f16x4 h1 = { (_Float16)o1.x, (_Float16)o1.y, (_Float16)o1.z, (_Float16)o1.w };
        *(f16x4*)&Kf[(size_t)(m0g + tm)     * H_ + n0g + tn] = h0;
        *(f16x4*)&Kf[(size_t)(m0g + tm + 1) * H_ + n0g + tn] = h1;
    } else if (z == 0) {
        *(float4*)&Qb[(size_t)(m0g + tm)     * H_ + n0g + tn] = o0;
        *(float4*)&Qb[(size_t)(m0g + tm + 1) * H_ + n0g + tn] = o1;
    } else {
        // V: transposed f16 [b][c][s]; rows tm,tm+1 are adjacent s -> one 4B store
        const int bb = m0g / S_;
        const int s0 = (m0g - bb * S_) + tm;
        _Float16* vt = Vtf + (size_t)bb * H_ * S_;
        const float* p0 = &o0.x;
        const float* p1 = &o1.x;
        #pragma unroll
        for (int j = 0; j < 4; ++j) {
            f16x2 pair = { (_Float16)p0[j], (_Float16)p1[j] };
            *(f16x2*)&vt[(size_t)(n0g + tn + j) * S_ + s0] = pair;
        }
    }
}

// ---------------- Kernel QW: build A matrix per (b,q) ----------------
// A[rowQ][h][0:256]   = f16(qW[h,e]) = f16(sum_d Q[rowQ,h*32+d] * Wr[e,h*32+d])
// A[rowQ][h][256:512] = (e>>5==h) ? f16(Q[rowQ,e]) : 0
__global__ __launch_bounds__(256) void qw_kernel(
    const float* __restrict__ Qb, const float* __restrict__ Wr,
    _Float16* __restrict__ Af)
{
    __shared__ __align__(16) float Qs[16][36];
    const int t = threadIdx.x;                // e index
    const int m0 = blockIdx.x * 16;
    const int h = blockIdx.y;

    float4 wr4[8];
    #pragma unroll
    for (int j = 0; j < 8; ++j)
        wr4[j] = *(const float4*)&Wr[(size_t)t * H_ + h * DH_ + j * 4];

    if (t < 128) {
        const int r = t >> 3, d4 = (t & 7) * 4;
        *(float4*)&Qs[r][d4] = *(const float4*)&Qb[(size_t)(m0 + r) * H_ + h * DH_ + d4];
    }
    __syncthreads();

    const bool own = ((t >> 5) == h);
    #pragma unroll 4
    for (int r = 0; r < 16; ++r) {
        float acc = 0.f;
        #pragma unroll
        for (int j = 0; j < 8; ++j) {
            const float4 qv = *(const float4*)&Qs[r][j * 4];
            acc += qv.x * wr4[j].x + qv.y * wr4[j].y + qv.z * wr4[j].z + qv.w * wr4[j].w;
        }
        _Float16* arow = Af + ((size_t)(m0 + r) * NH_ + h) * 512;
        arow[t] = (_Float16)acc;
        arow[256 + t] = own ? (_Float16)Qs[r][t & 31] : (_Float16)0.0f;
    }
}

// ---------------- Kernel B: MFMA scores + mask + softmax + fast PV ----------------
// Champion score loop (byte-identical memory structure). Changes vs R10 champion:
//   - PV reads transposed f16 V (contiguous per thread, f16x8) + float4 p-reads
//   - softmax->PV barrier dropped (PV reads only own-wave softmax rows)
//   - limit==0 path served from Vtf
__global__ __launch_bounds__(256) void attn_kernel(
    const float* __restrict__ rpe, const _Float16* __restrict__ Af,
    const _Float16* __restrict__ Kf, const _Float16* __restrict__ Vtf,
    const int* __restrict__ seq_len, const int* __restrict__ lex_num,
    float* __restrict__ out)
{
    __shared__ float sc[NH_ * PADK];
    __shared__ __align__(16) _Float16 stg[4][16][256];
    const int blk = blockIdx.x;
    const int b = blk / S_;
    const int q = blk - b * S_;
    const int t = threadIdx.x;
    const int lane = t & 63;
    const int wave = t >> 6;
    int limit = seq_len[b] + lex_num[b];
    limit = limit < 0 ? 0 : (limit > S_ ? S_ : limit);
    const size_t rowQ = (size_t)(b * S_ + q);

    if (limit == 0) {
        const _Float16* vrow = Vtf + ((size_t)b * H_ + t) * S_;
        float acc = 0.f;
        for (int s = 0; s < S_; s += 8) {
            const f16x8 v8 = *(const f16x8*)(vrow + s);
            #pragma unroll
            for (int u = 0; u < 8; ++u) acc += (float)v8[u];
        }
        out[rowQ * H_ + t] = acc * (1.0f / S_);
        return;
    }

    const int r = lane & 15;     // fragment row: A-row (head) / key within tile
    const int g = lane >> 4;     // k-group within fragment

    // ---- hoist A-fragments for all 16 contraction steps (64 VGPR) ----
    f16x8 afrag[16];
    {
        const _Float16* Arow = Af + rowQ * (NH_ * 512) + (size_t)r * 512;
        if (r < NH_) {
            #pragma unroll
            for (int j = 0; j < 16; ++j)
                afrag[j] = *(const f16x8*)(Arow + j * 32 + g * 8);
        } else {
            #pragma unroll
            for (int j = 0; j < 16; ++j)
                afrag[j] = (f16x8){};
        }
    }

    char* myl = (char*)&stg[wave][0][0];
    const int swzr = (r & 7) << 4;
    const float* rpe_base = rpe + rowQ * (size_t)S_ * H_;
    const int ntiles = (limit + 15) >> 4;

    for (int kt = wave; kt < ntiles; kt += 4) {
        const int k0 = kt * 16;
        const float* gsrc = rpe_base + (size_t)k0 * H_;
        // ---- stage 16 rows (f32 -> f16, swizzled) ----
        #pragma unroll
        for (int half = 0; half < 2; ++half) {
            float4 v[8];
            #pragma unroll
            for (int rr = 0; rr < 8; ++rr)
                v[rr] = *(const float4*)&gsrc[(size_t)(half * 8 + rr) * H_ + lane * 4];
            #pragma unroll
            for (int rr = 0; rr < 8; ++rr) {
                const int row = half * 8 + rr;
                f16x4 hv = { (_Float16)v[rr].x, (_Float16)v[rr].y,
                             (_Float16)v[rr].z, (_Float16)v[rr].w };
                *(f16x4*)(myl + row * 512 + ((lane * 8) ^ ((row & 7) << 4))) = hv;
            }
        }
        // ---- MFMA: 8 rpe steps (LDS) + 8 K steps ----
        f32x4 acc = {};
        #pragma unroll
        for (int j = 0; j < 8; ++j) {
            f16x8 bf = *(const f16x8*)(myl + r * 512 + ((j * 64 + g * 16) ^ swzr));
            acc = __builtin_amdgcn_mfma_f32_16x16x32_f16(afrag[j], bf, acc, 0, 0, 0);
        }
        const _Float16* krow = Kf + ((size_t)(b * S_ + k0 + r)) * H_ + g * 8;
        #pragma unroll
        for (int j = 0; j < 8; ++j) {
            const f16x8 kf = *(const f16x8*)(krow + j * 32);
            acc = __builtin_amdgcn_mfma_f32_16x16x32_f16(afrag[8 + j], kf, acc, 0, 0, 0);
        }
        // ---- write scores: lanes 0..31 hold heads 0..7 (C: col=lane&15, row=g*4+i) ----
        if (lane < 32) {
            #pragma unroll
            for (int i = 0; i < 4; ++i)
                sc[(g * 4 + i) * PADK + k0 + r] = acc[i];
        }
    }
    __syncthreads();   // scores are striped across waves -> full barrier needed

    // ---- softmax: wave w owns heads 2w, 2w+1 ----
    for (int hh = 0; hh < 2; ++hh) {
        const int h = wave * 2 + hh;
        float s0[6];
        #pragma unroll
        for (int j = 0; j < 6; ++j) {
            const int k = lane + 64 * j;
            s0[j] = (k < limit) ? sc[h * PADK + k] : -1e15f;
        }
        float mx = s0[0];
        #pragma unroll
        for (int j = 1; j < 6; ++j) mx = fmaxf(mx, s0[j]);
        #pragma unroll
        for (int m = 1; m < 64; m <<= 1) mx = fmaxf(mx, __shfl_xor(mx, m, 64));
        float p[6]; float sum = 0.f;
        #pragma unroll
        for (int j = 0; j < 6; ++j) {
            const int k = lane + 64 * j;
            p[j] = (k < limit) ? __expf(s0[j] - mx) : 0.f;
            sum += p[j];
        }
        #pragma unroll
        for (int m = 1; m < 64; m <<= 1) sum += __shfl_xor(sum, m, 64);
        const float inv = 1.0f / sum;
        #pragma unroll
        for (int j = 0; j < 6; ++j) sc[h * PADK + lane + 64 * j] = p[j] * inv;
    }
    // NO barrier: PV thread t reads heads 2w,2w+1 of its own wave only;
    // within-wave DS ordering guarantees visibility.

    // ---- PV: thread t -> (h = t>>5, d = t&31); V transposed f16, contiguous k ----
    {
        const int h = t >> 5;
        const int d = t & 31;
        const _Float16* vrow = Vtf + ((size_t)b * H_ + h * DH_ + d) * S_;
        const float* prow = &sc[h * PADK];
        float acc = 0.f;
        int k = 0;
        for (; k + 8 <= limit; k += 8) {
            const f16x8 v8 = *(const f16x8*)(vrow + k);
            const float4 p0 = *(const float4*)(prow + k);
            const float4 p1 = *(const float4*)(prow + k + 4);
            acc += (float)v8[0] * p0.x + (float)v8[1] * p0.y
                 + (float)v8[2] * p0.z + (float)v8[3] * p0.w
                 + (float)v8[4] * p1.x + (float)v8[5] * p1.y
                 + (float)v8[6] * p1.z + (float)v8[7] * p1.w;
        }
        for (; k < limit; ++k) acc += (float)vrow[k] * prow[k];
        out[rowQ * H_ + h * DH_ + d] = acc;
    }
}

extern "C" void kernel_launch(void* const* d_in, const int* in_sizes, int n_in,
                              void* d_out, int out_size, void* d_ws, size_t ws_size,
                              hipStream_t stream)
{
    const float* key   = (const float*)d_in[0];
    const float* query = (const float*)d_in[1];
    const float* value = (const float*)d_in[2];
    const float* rpe   = (const float*)d_in[3];
    const int* seq_len = (const int*)d_in[4];
    const int* lex_num = (const int*)d_in[5];
    const float* Wk = (const float*)d_in[6];
    const float* bk = (const float*)d_in[7];
    const float* Wq = (const float*)d_in[8];
    const float* bq = (const float*)d_in[9];
    const float* Wv = (const float*)d_in[10];
    const float* bv = (const float*)d_in[11];
    const float* Wr = (const float*)d_in[12];
    const float* br = (const float*)d_in[13];
    (void)bk; (void)br;

    const size_t NTOK = (size_t)B_ * S_;          // 1536
    float* w = (float*)d_ws;
    float* Qb = w;                                 // f32 [1536*256]
    _Float16* Kf = (_Float16*)(Qb + NTOK * H_);    // f16 [1536*256]
    _Float16* Af = Kf + NTOK * H_;                 // f16 [1536*8*512]
    _Float16* Vtf = Af + NTOK * NH_ * 512;         // f16 [4*256*384]

    proj_kernel<<<dim3(48, 4, 3), dim3(256), 0, stream>>>(
        query, key, value, Wq, bq, Wk, bk, Wv, bv, Qb, Kf, Vtf);
    qw_kernel<<<dim3(96, 8), dim3(256), 0, stream>>>(Qb, Wr, Af);
    attn_kernel<<<dim3(1536), dim3(256), 0, stream>>>(
        rpe, Af, Kf, Vtf, seq_len, lex_num, (float*)d_out);
}